// Round 1
// baseline (465.561 us; speedup 1.0000x reference)
//
#include <hip/hip_runtime.h>
#include <hip/hip_bf16.h>
#include <math.h>

// ---------------- complex double helpers (prep only) ----------------
struct cd { double x, y; };
__device__ __forceinline__ cd cmul(cd a, cd b){ return {a.x*b.x - a.y*b.y, a.x*b.y + a.y*b.x}; }
__device__ __forceinline__ cd cconj(cd a){ return {a.x, -a.y}; }
__device__ __forceinline__ cd cadd(cd a, cd b){ return {a.x+b.x, a.y+b.y}; }

// S[d'*4+d] = sum_K K[i',a] * conj(K[j',b]),  d'=2i'+j', d=2a+b
__device__ void superop_from_kraus(cd S[16], const cd* Ks, int nk){
    for (int i=0;i<16;i++) S[i] = {0.0,0.0};
    for (int n=0;n<nk;n++){
        const cd* K = Ks + n*4;
        for (int ip=0; ip<2; ip++) for (int jp=0; jp<2; jp++)
        for (int a=0; a<2; a++)   for (int b=0; b<2; b++){
            cd t = cmul(K[ip*2+a], cconj(K[jp*2+b]));
            int idx = (ip*2+jp)*4 + (a*2+b);
            S[idx] = cadd(S[idx], t);
        }
    }
}

__device__ void mm4(cd C[16], const cd A[16], const cd B[16]){
    for (int i=0;i<4;i++) for (int j=0;j<4;j++){
        cd s = {0.0,0.0};
        for (int k=0;k<4;k++) s = cadd(s, cmul(A[i*4+k], B[k*4+j]));
        C[i*4+j] = s;
    }
}

__device__ void build_dep(cd* dep, double p){
    double a = sqrt(1.0-p), b = sqrt(p/3.0);
    // I
    dep[0]={a,0};  dep[1]={0,0};   dep[2]={0,0};  dep[3]={a,0};
    // X
    dep[4]={0,0};  dep[5]={b,0};   dep[6]={b,0};  dep[7]={0,0};
    // Y
    dep[8]={0,0};  dep[9]={0,-b};  dep[10]={0,b}; dep[11]={0,0};
    // Z
    dep[12]={b,0}; dep[13]={0,0};  dep[14]={0,0}; dep[15]={-b,0};
}

// ---------------- prep: build all superops ----------------
// rot_s[30][16]: fused (phase*amp*depol1*Rot) per (layer,qubit)
// cnot_t[256]:   fused (noise_q (x) noise_t) * (CNOT (x) CNOT)  -- constant
// bf_s[16]:      readout bitflip superop
__global__ void prep_kernel(const float* __restrict__ wts, float2* rot_s, float2* cnot_t, float2* bf_s){
    int tid = threadIdx.x;
    const double P1 = 0.001, P2 = 0.01, PR = 0.02;
    const double GA = 1.0 - exp(-1e-7/0.05);
    const double GP = 1.0 - exp(-1e-7/0.07);

    cd amp[8], ph[8], krbuf[16];
    {
        double s1 = sqrt(1.0-GA), s2 = sqrt(GA);
        amp[0]={1,0}; amp[1]={0,0}; amp[2]={0,0}; amp[3]={s1,0};
        amp[4]={0,0}; amp[5]={s2,0}; amp[6]={0,0}; amp[7]={0,0};
    }
    {
        double s1 = sqrt(1.0-GP), s2 = sqrt(GP);
        ph[0]={1,0}; ph[1]={0,0}; ph[2]={0,0}; ph[3]={s1,0};
        ph[4]={0,0}; ph[5]={0,0}; ph[6]={0,0}; ph[7]={s2,0};
    }
    cd Sdep[16], Samp[16], Sph[16], N1[16], N2[16], tmp[16];
    superop_from_kraus(Samp, amp, 2);
    superop_from_kraus(Sph, ph, 2);
    build_dep(krbuf, P1); superop_from_kraus(Sdep, krbuf, 4);
    mm4(tmp, Samp, Sdep); mm4(N1, Sph, tmp);        // N1 = Sph*Samp*Sdep1
    build_dep(krbuf, P2); superop_from_kraus(Sdep, krbuf, 4);
    mm4(tmp, Samp, Sdep); mm4(N2, Sph, tmp);        // N2 = Sph*Samp*Sdep2

    if (tid < 30){
        // tid = l*10+q matches (3,10,3) row-major flattening
        double phi = wts[tid*3+0], th = wts[tid*3+1], om = wts[tid*3+2];
        double ct = cos(0.5*th), st = sin(0.5*th);
        cd ep = {cos(0.5*(phi+om)), -sin(0.5*(phi+om))};   // exp(-0.5i(phi+om))
        cd em = {cos(0.5*(phi-om)),  sin(0.5*(phi-om))};   // exp(+0.5i(phi-om))
        cd R[4];
        R[0] = { ep.x*ct,  ep.y*ct};
        R[1] = {-em.x*st, -em.y*st};
        R[2] = { em.x*st, -em.y*st};   // conj(em)*s
        R[3] = { ep.x*ct, -ep.y*ct};   // conj(ep)*c
        cd Sr[16];
        for (int i2=0;i2<2;i2++) for (int j2=0;j2<2;j2++)
        for (int a=0;a<2;a++)    for (int b2=0;b2<2;b2++)
            Sr[(i2*2+j2)*4 + (a*2+b2)] = cmul(R[i2*2+a], cconj(R[j2*2+b2]));
        cd S[16]; mm4(S, N1, Sr);
        for (int i=0;i<16;i++) rot_s[tid*16+i] = make_float2((float)S[i].x, (float)S[i].y);
    }
    if (tid == 30){
        cd bf[8];
        double a = sqrt(1.0-PR), b = sqrt(PR);
        bf[0]={a,0}; bf[1]={0,0}; bf[2]={0,0}; bf[3]={a,0};
        bf[4]={0,0}; bf[5]={b,0}; bf[6]={b,0}; bf[7]={0,0};
        cd S[16]; superop_from_kraus(S, bf, 2);
        for (int i=0;i<16;i++) bf_s[i] = make_float2((float)S[i].x, (float)S[i].y);
    }
    // CNOT block: every thread computes one of the 256 entries
    {
        int Dp = tid >> 4, D = tid & 15;
        const int PCN[4] = {0,1,3,2};        // CNOT permutation (control,target)
        int dqp = ((Dp>>3)&1)*2 + ((Dp>>1)&1);
        int dtp = ((Dp>>2)&1)*2 + (Dp&1);
        int k2d = D>>2, b2d = D&3;
        cd s = {0.0,0.0};
        for (int M=0; M<16; M++){
            int k2m = M>>2, b2m = M&3;
            if (k2d != PCN[k2m] || b2d != PCN[b2m]) continue;  // C16[M][D] == 1 here
            int dqm = ((M>>3)&1)*2 + ((M>>1)&1);
            int dtm = ((M>>2)&1)*2 + (M&1);
            cd nn = cmul(N2[dqp*4+dqm], N2[dtp*4+dtm]);
            s = cadd(s, nn);
        }
        cnot_t[tid] = make_float2((float)s.x, (float)s.y);
    }
}

// ---------------- rho init ----------------
__global__ void init_rho(float2* __restrict__ rho){
    unsigned i = blockIdx.x*blockDim.x + threadIdx.x;
    rho[i] = (i==0) ? make_float2(1.f,0.f) : make_float2(0.f,0.f);
}

__device__ __forceinline__ unsigned expandbit(unsigned x, int b){
    return ((x >> b) << (b+1)) | (x & ((1u<<b)-1u));
}

// ---------------- 1-qubit superop, in place ----------------
__global__ __launch_bounds__(256) void apply1q(float2* __restrict__ rho, const float2* __restrict__ S,
                                               int bi, int bj){
    __shared__ float2 s[16];
    if (threadIdx.x < 16) s[threadIdx.x] = S[threadIdx.x];
    __syncthreads();
    unsigned t = blockIdx.x*256u + threadIdx.x;          // 2^18 threads
    unsigned x = expandbit(expandbit(t, bj), bi);
    unsigned Bi = 1u<<bi, Bj = 1u<<bj;
    float2 v[4];
    v[0] = rho[x]; v[1] = rho[x+Bj]; v[2] = rho[x+Bi]; v[3] = rho[x+Bi+Bj];
    float2 o[4];
#pragma unroll
    for (int dp=0; dp<4; dp++){
        float re=0.f, im=0.f;
#pragma unroll
        for (int d=0; d<4; d++){
            float2 m = s[dp*4+d];
            re += m.x*v[d].x - m.y*v[d].y;
            im += m.x*v[d].y + m.y*v[d].x;
        }
        o[dp] = make_float2(re, im);
    }
    rho[x] = o[0]; rho[x+Bj] = o[1]; rho[x+Bi] = o[2]; rho[x+Bi+Bj] = o[3];
}

// ---------------- 2-qubit (CNOT+noise) superop, in place ----------------
__global__ __launch_bounds__(256) void apply2q(float2* __restrict__ rho, const float2* __restrict__ T,
                                               int s0,int s1,int s2,int s3,
                                               int bqi,int bti,int bqj,int btj){
    __shared__ float2 sT[256];
    sT[threadIdx.x] = T[threadIdx.x];
    __syncthreads();
    unsigned t = blockIdx.x*256u + threadIdx.x;          // 2^16 threads
    unsigned x = expandbit(expandbit(expandbit(expandbit(t, s0), s1), s2), s3);
    unsigned offs[16];
    float2 v[16];
#pragma unroll
    for (int D=0; D<16; D++){
        unsigned o = (((D>>3)&1u)<<bqi) | (((D>>2)&1u)<<bti) | (((D>>1)&1u)<<bqj) | ((D&1u)<<btj);
        offs[D] = o;
        v[D] = rho[x + o];
    }
#pragma unroll
    for (int Dp=0; Dp<16; Dp++){
        float re=0.f, im=0.f;
#pragma unroll
        for (int D=0; D<16; D++){
            float2 m = sT[Dp*16+D];
            re += m.x*v[D].x - m.y*v[D].y;
            im += m.x*v[D].y + m.y*v[D].x;
        }
        rho[x + offs[Dp]] = make_float2(re, im);
    }
}

// ---------------- traces: c[k] = w[k] * Re tr(P_k rho) ----------------
__global__ __launch_bounds__(256) void trace_kernel(const float2* __restrict__ rho,
                                                    const float* __restrict__ w,
                                                    float* __restrict__ c){
    int k = blockIdx.x;            // 20 blocks; k=2q -> X_q, k=2q+1 -> Z_q
    int q = k >> 1;
    unsigned bit = 1u << (9 - q);
    int tid = threadIdx.x;
    float acc = 0.f;
#pragma unroll
    for (int r=0; r<4; r++){
        unsigned m = tid + r*256;
        if (k & 1){
            float d = rho[m*1024u + m].x;
            acc += (m & bit) ? -d : d;
        } else {
            acc += rho[(m ^ bit)*1024u + m].x;
        }
    }
    for (int o=32; o>0; o>>=1) acc += __shfl_down(acc, o);
    __shared__ float p[4];
    if ((tid & 63) == 0) p[tid>>6] = acc;
    __syncthreads();
    if (tid == 0) c[k] = w[k] * (p[0]+p[1]+p[2]+p[3]);
}

// ---------------- head: logits + sigmoid ----------------
__global__ __launch_bounds__(256) void logits_kernel(const float* __restrict__ x,
                                                     const float* __restrict__ bvec,
                                                     const float* __restrict__ c,
                                                     float* __restrict__ out){
    __shared__ float xs[1024];
    __shared__ float cX[10], cZ[10];
    int b = blockIdx.x, tid = threadIdx.x;
    if (tid < 10){ cX[tid] = c[2*tid]; cZ[tid] = c[2*tid+1]; }
#pragma unroll
    for (int r=0; r<4; r++){
        int m = tid + r*256;
        xs[m] = x[b*1024 + m] + bvec[m];
    }
    __syncthreads();
    float acc = 0.f;
#pragma unroll
    for (int r=0; r<4; r++){
        int m = tid + r*256;
        float xm = xs[m];
        float sd = 0.f;
#pragma unroll
        for (int q=0; q<10; q++){
            float cz = cZ[q];
            sd += (m & (1<<(9-q))) ? -cz : cz;
            acc += cX[q] * xm * xs[m ^ (1<<(9-q))];
        }
        acc += sd * xm * xm;
    }
    for (int o=32; o>0; o>>=1) acc += __shfl_down(acc, o);
    __shared__ float p[4];
    if ((tid & 63) == 0) p[tid>>6] = acc;
    __syncthreads();
    if (tid == 0){
        float l = p[0]+p[1]+p[2]+p[3];
        out[b] = 1.f / (1.f + expf(-l));
    }
}

// ---------------- launch ----------------
extern "C" void kernel_launch(void* const* d_in, const int* in_sizes, int n_in,
                              void* d_out, int out_size, void* d_ws, size_t ws_size,
                              hipStream_t stream) {
    const float* x    = (const float*)d_in[0];   // [2048,1024]
    const float* bvec = (const float*)d_in[1];   // [1024]
    const float* w    = (const float*)d_in[2];   // [20]
    const float* cw   = (const float*)d_in[3];   // [3,10,3]
    // d_in[4] = P_tensor: unused (Pauli sparsity exploited analytically)
    float* out = (float*)d_out;

    char* ws = (char*)d_ws;
    float2* rho    = (float2*)ws;                         // 2^20 float2 = 8 MB
    float2* rot_s  = (float2*)(ws + (1u<<20)*sizeof(float2));
    float2* cnot_t = rot_s + 30*16;
    float2* bf_s   = cnot_t + 256;
    float*  cvec   = (float*)(bf_s + 16);
    (void)ws_size; (void)in_sizes; (void)n_in; (void)out_size;

    prep_kernel<<<1, 256, 0, stream>>>(cw, rot_s, cnot_t, bf_s);
    init_rho<<<4096, 256, 0, stream>>>(rho);

    for (int l=0; l<3; l++){
        for (int q=0; q<10; q++)
            apply1q<<<1024, 256, 0, stream>>>(rho, rot_s + (l*10+q)*16, 19-q, 9-q);
        for (int q=0; q<10; q++){
            int tq = (q+1)%10;
            int bqi=19-q, bqj=9-q, bti=19-tq, btj=9-tq;
            int bits[4] = {bqi, bqj, bti, btj};
            for (int a=0;a<3;a++) for (int b2=a+1;b2<4;b2++)
                if (bits[b2] < bits[a]){ int tmpb=bits[a]; bits[a]=bits[b2]; bits[b2]=tmpb; }
            apply2q<<<256, 256, 0, stream>>>(rho, cnot_t,
                                             bits[0], bits[1], bits[2], bits[3],
                                             bqi, bti, bqj, btj);
        }
    }
    for (int q=0; q<10; q++)
        apply1q<<<1024, 256, 0, stream>>>(rho, bf_s, 19-q, 9-q);

    trace_kernel<<<20, 256, 0, stream>>>(rho, w, cvec);
    logits_kernel<<<2048, 256, 0, stream>>>(x, bvec, cvec, out);
}

// Round 2
// 176.002 us; speedup vs baseline: 2.6452x; 2.6452x over previous
//
#include <hip/hip_runtime.h>
#include <hip/hip_bf16.h>
#include <math.h>

// ================= complex double helpers (prep only) =================
struct cd { double x, y; };
__device__ __forceinline__ cd cmul(cd a, cd b){ return {a.x*b.x - a.y*b.y, a.x*b.y + a.y*b.x}; }
__device__ __forceinline__ cd cconj(cd a){ return {a.x, -a.y}; }
__device__ __forceinline__ cd cadd(cd a, cd b){ return {a.x+b.x, a.y+b.y}; }

// S[d'*4+d] = sum_K K[i',a] * conj(K[j',b]),  d'=2i'+j', d=2a+b  (ket = high bit)
__device__ void superop_from_kraus(cd S[16], const cd* Ks, int nk){
    for (int i=0;i<16;i++) S[i] = {0.0,0.0};
    for (int n=0;n<nk;n++){
        const cd* K = Ks + n*4;
        for (int ip=0; ip<2; ip++) for (int jp=0; jp<2; jp++)
        for (int a=0; a<2; a++)   for (int b=0; b<2; b++){
            cd t = cmul(K[ip*2+a], cconj(K[jp*2+b]));
            int idx = (ip*2+jp)*4 + (a*2+b);
            S[idx] = cadd(S[idx], t);
        }
    }
}

__device__ void mm4(cd C[16], const cd A[16], const cd B[16]){
    for (int i=0;i<4;i++) for (int j=0;j<4;j++){
        cd s = {0.0,0.0};
        for (int k=0;k<4;k++) s = cadd(s, cmul(A[i*4+k], B[k*4+j]));
        C[i*4+j] = s;
    }
}

__device__ void build_dep(cd* dep, double p){
    double a = sqrt(1.0-p), b = sqrt(p/3.0);
    dep[0]={a,0};  dep[1]={0,0};   dep[2]={0,0};  dep[3]={a,0};    // I
    dep[4]={0,0};  dep[5]={b,0};   dep[6]={b,0};  dep[7]={0,0};    // X
    dep[8]={0,0};  dep[9]={0,-b};  dep[10]={0,b}; dep[11]={0,0};   // Y
    dep[12]={b,0}; dep[13]={0,0};  dep[14]={0,0}; dep[15]={-b,0};  // Z
}

// ============ prep: mats[0..29] = N1*Rot per (layer,qubit); mats[30] = N2 ============
__global__ void prep_kernel(const float* __restrict__ wts, float2* __restrict__ mats){
    int tid = threadIdx.x;
    const double P1 = 0.001, P2 = 0.01;
    const double GA = 1.0 - exp(-1e-7/0.05);
    const double GP = 1.0 - exp(-1e-7/0.07);

    cd amp[8], ph[8], krbuf[16];
    {
        double s1 = sqrt(1.0-GA), s2 = sqrt(GA);
        amp[0]={1,0}; amp[1]={0,0}; amp[2]={0,0}; amp[3]={s1,0};
        amp[4]={0,0}; amp[5]={s2,0}; amp[6]={0,0}; amp[7]={0,0};
    }
    {
        double s1 = sqrt(1.0-GP), s2 = sqrt(GP);
        ph[0]={1,0}; ph[1]={0,0}; ph[2]={0,0}; ph[3]={s1,0};
        ph[4]={0,0}; ph[5]={0,0}; ph[6]={0,0}; ph[7]={s2,0};
    }
    cd Sdep[16], Samp[16], Sph[16], N1[16], N2[16], tmp[16];
    superop_from_kraus(Samp, amp, 2);
    superop_from_kraus(Sph, ph, 2);
    build_dep(krbuf, P1); superop_from_kraus(Sdep, krbuf, 4);
    mm4(tmp, Samp, Sdep); mm4(N1, Sph, tmp);        // N1 = Sph*Samp*Sdep1
    build_dep(krbuf, P2); superop_from_kraus(Sdep, krbuf, 4);
    mm4(tmp, Samp, Sdep); mm4(N2, Sph, tmp);        // N2 = Sph*Samp*Sdep2

    if (tid < 30){
        double phi = wts[tid*3+0], th = wts[tid*3+1], om = wts[tid*3+2];
        double ct = cos(0.5*th), st = sin(0.5*th);
        cd ep = {cos(0.5*(phi+om)), -sin(0.5*(phi+om))};   // exp(-0.5i(phi+om))
        cd em = {cos(0.5*(phi-om)),  sin(0.5*(phi-om))};   // exp(+0.5i(phi-om))
        cd R[4];
        R[0] = { ep.x*ct,  ep.y*ct};
        R[1] = {-em.x*st, -em.y*st};
        R[2] = { em.x*st, -em.y*st};
        R[3] = { ep.x*ct, -ep.y*ct};
        cd Sr[16];
        for (int i2=0;i2<2;i2++) for (int j2=0;j2<2;j2++)
        for (int a=0;a<2;a++)    for (int b2=0;b2<2;b2++)
            Sr[(i2*2+j2)*4 + (a*2+b2)] = cmul(R[i2*2+a], cconj(R[j2*2+b2]));
        cd S[16]; mm4(S, N1, Sr);
        for (int i=0;i<16;i++) mats[tid*16+i] = make_float2((float)S[i].x, (float)S[i].y);
    }
    if (tid == 30){
        for (int i=0;i<16;i++) mats[30*16+i] = make_float2((float)N2[i].x, (float)N2[i].y);
    }
}

// ============ fused multi-op kernel ============
// rho layout (internal): digit j (= 9 - gate_qubit q) at bits (2j [bra], 2j+1 [ket]).
struct FusedCfg {
    unsigned um0, um1; int us0, us1;   // tile-index -> global scatter
    int bs0;                          // blockIdx << bs0 = block offset
    int nops, doInit;
    int pa[4], pb[4], preA[4], preB[4];  // t-bit positions; pre* = float2 offset into mats, -1 = none
};

#define CMUL_ACC(re,im,m,a) { re += (m).x*(a).x - (m).y*(a).y; im += (m).x*(a).y + (m).y*(a).x; }

#define ALONG_A(Mp) { _Pragma("unroll") for (int db_=0; db_<4; db_++){ \
    float2 a0=v[db_], a1=v[4+db_], a2=v[8+db_], a3=v[12+db_]; \
    _Pragma("unroll") for (int dp_=0; dp_<4; dp_++){ \
        float re=0.f, im=0.f; \
        CMUL_ACC(re,im,(Mp)[dp_*4+0],a0); CMUL_ACC(re,im,(Mp)[dp_*4+1],a1); \
        CMUL_ACC(re,im,(Mp)[dp_*4+2],a2); CMUL_ACC(re,im,(Mp)[dp_*4+3],a3); \
        v[dp_*4+db_] = make_float2(re,im); } } }

#define ALONG_B(Mp) { _Pragma("unroll") for (int da_=0; da_<4; da_++){ \
    float2 a0=v[da_*4+0], a1=v[da_*4+1], a2=v[da_*4+2], a3=v[da_*4+3]; \
    _Pragma("unroll") for (int dp_=0; dp_<4; dp_++){ \
        float re=0.f, im=0.f; \
        CMUL_ACC(re,im,(Mp)[dp_*4+0],a0); CMUL_ACC(re,im,(Mp)[dp_*4+1],a1); \
        CMUL_ACC(re,im,(Mp)[dp_*4+2],a2); CMUL_ACC(re,im,(Mp)[dp_*4+3],a3); \
        v[da_*4+dp_] = make_float2(re,im); } } }

__global__ __launch_bounds__(256) void fused_ops(float2* __restrict__ rho,
                                                 const float2* __restrict__ mats,
                                                 FusedCfg c){
    __shared__ __align__(16) float2 tile[4096];
    __shared__ float2 sm[31*16];
    int tid = threadIdx.x;
    for (int k = tid; k < 496; k += 256) sm[k] = mats[k];
    unsigned bo = ((unsigned)blockIdx.x) << c.bs0;

    if (c.doInit){
#pragma unroll
        for (int r=0; r<16; r++){
            unsigned u = tid + 256u*r;
            float val = (blockIdx.x==0 && u==0) ? 1.f : 0.f;
            tile[u ^ ((u>>6)&62u)] = make_float2(val, 0.f);
        }
    } else {
#pragma unroll
        for (int r=0; r<8; r++){
            unsigned u = 2u*(tid + 256u*r);
            unsigned g = bo + ((u & c.um0) << c.us0) + ((u & c.um1) << c.us1);
            unsigned s = u ^ ((u>>6)&62u);
            *reinterpret_cast<float4*>(&tile[s]) = *reinterpret_cast<const float4*>(rho + g);
        }
    }
    __syncthreads();

#pragma unroll
    for (int op=0; op<4; op++){
        if (op < c.nops){
            int pa = c.pa[op], pb = c.pb[op];
            int lo = pa < pb ? pa : pb, hi = pa < pb ? pb : pa;
            unsigned g8 = (unsigned)tid;
            unsigned x = ((g8 >> lo) << (lo+2)) | (g8 & ((1u<<lo)-1u));
            x = ((x >> hi) << (hi+2)) | (x & ((1u<<hi)-1u));
            unsigned adr[16];
            float2 v[16];
#pragma unroll
            for (int d=0; d<16; d++){
                unsigned t = x | ((unsigned)(d>>2) << pa) | ((unsigned)(d&3) << pb);
                adr[d] = t ^ ((t>>6)&62u);
                v[d] = tile[adr[d]];
            }
            int mA = c.preA[op], mB = c.preB[op];
            if (mA >= 0) { const float2* M = sm + mA; ALONG_A(M); }
            if (mB >= 0) { const float2* M = sm + mB; ALONG_B(M); }
            { // CNOT perm: v[da][db] <- v[da][db^da]
                float2 t0;
                t0=v[4];  v[4]=v[5];   v[5]=t0;
                t0=v[6];  v[6]=v[7];   v[7]=t0;
                t0=v[8];  v[8]=v[10];  v[10]=t0;
                t0=v[9];  v[9]=v[11];  v[11]=t0;
                t0=v[12]; v[12]=v[15]; v[15]=t0;
                t0=v[13]; v[13]=v[14]; v[14]=t0;
            }
            { const float2* M = sm + 30*16; ALONG_B(M); ALONG_A(M); }  // N2 on target, N2 on control
#pragma unroll
            for (int d=0; d<16; d++) tile[adr[d]] = v[d];
        }
        __syncthreads();
    }

#pragma unroll
    for (int r=0; r<8; r++){
        unsigned u = 2u*(tid + 256u*r);
        unsigned g = bo + ((u & c.um0) << c.us0) + ((u & c.um1) << c.us1);
        unsigned s = u ^ ((u>>6)&62u);
        *reinterpret_cast<float4*>(rho + g) = *reinterpret_cast<const float4*>(&tile[s]);
    }
}

// ============ traces: c[k] = w[k] * (readout factor) * Re tr(P_k rho) ============
__global__ __launch_bounds__(256) void trace_kernel(const float2* __restrict__ rho,
                                                    const float* __restrict__ w,
                                                    float* __restrict__ c){
    int k = blockIdx.x;            // k=2q -> X_q, k=2q+1 -> Z_q
    int q = k >> 1;
    int j = 9 - q;                 // digit index
    int tid = threadIdx.x;
    float acc = 0.f;
#pragma unroll
    for (int r=0; r<4; r++){
        unsigned m = tid + 256u*r;
        unsigned x = m;
        x = (x | (x<<8)) & 0x00FF00FFu;
        x = (x | (x<<4)) & 0x0F0F0F0Fu;
        x = (x | (x<<2)) & 0x33333333u;
        x = (x | (x<<1)) & 0x55555555u;
        unsigned diag = 3u*x;      // ket=bra=m, interleaved
        if (k & 1){
            float d = rho[diag].x;
            acc += ((m >> j) & 1u) ? -d : d;
        } else {
            acc += rho[diag ^ (1u << (2*j+1))].x;
        }
    }
    for (int o=32; o>0; o>>=1) acc += __shfl_down(acc, o);
    __shared__ float p[4];
    if ((tid & 63) == 0) p[tid>>6] = acc;
    __syncthreads();
    if (tid == 0){
        float scale = (k & 1) ? 0.96f : 1.0f;   // readout bitflip folded: Z *= 1-2*0.02
        c[k] = w[k] * scale * (p[0]+p[1]+p[2]+p[3]);
    }
}

// ============ head: logits + sigmoid ============
__global__ __launch_bounds__(256) void logits_kernel(const float* __restrict__ x,
                                                     const float* __restrict__ bvec,
                                                     const float* __restrict__ c,
                                                     float* __restrict__ out){
    __shared__ float xs[1024];
    __shared__ float cX[10], cZ[10];
    int b = blockIdx.x, tid = threadIdx.x;
    if (tid < 10){ cX[tid] = c[2*tid]; cZ[tid] = c[2*tid+1]; }
#pragma unroll
    for (int r=0; r<4; r++){
        int m = tid + r*256;
        xs[m] = x[b*1024 + m] + bvec[m];
    }
    __syncthreads();
    float acc = 0.f;
#pragma unroll
    for (int r=0; r<4; r++){
        int m = tid + r*256;
        float xm = xs[m];
        float sd = 0.f;
#pragma unroll
        for (int q=0; q<10; q++){
            float cz = cZ[q];
            sd += (m & (1<<(9-q))) ? -cz : cz;
            acc += cX[q] * xm * xs[m ^ (1<<(9-q))];
        }
        acc += sd * xm * xm;
    }
    for (int o=32; o>0; o>>=1) acc += __shfl_down(acc, o);
    __shared__ float p[4];
    if ((tid & 63) == 0) p[tid>>6] = acc;
    __syncthreads();
    if (tid == 0){
        float l = p[0]+p[1]+p[2]+p[3];
        out[b] = 1.f / (1.f + expf(-l));
    }
}

// ============ launch ============
extern "C" void kernel_launch(void* const* d_in, const int* in_sizes, int n_in,
                              void* d_out, int out_size, void* d_ws, size_t ws_size,
                              hipStream_t stream) {
    const float* x    = (const float*)d_in[0];   // [2048,1024]
    const float* bvec = (const float*)d_in[1];   // [1024]
    const float* w    = (const float*)d_in[2];   // [20]
    const float* cw   = (const float*)d_in[3];   // [3,10,3]
    float* out = (float*)d_out;

    char* ws = (char*)d_ws;
    float2* rho  = (float2*)ws;                              // 2^20 float2 = 8 MB
    float2* mats = (float2*)(ws + (1u<<20)*sizeof(float2));  // 31*16 float2
    float*  cvec = (float*)(mats + 31*16);
    (void)ws_size; (void)in_sizes; (void)n_in; (void)out_size;

    prep_kernel<<<1, 64, 0, stream>>>(cw, mats);

    // Per layer: K1 digits{9..5}: CNOT(0,1)..(3,4); K2 digits{5..1}: CNOT(4,5)..(7,8);
    //            K3 digits{1,0,9}: CNOT(8,9),(9,0).  Rotations folded as pre-matrices.
    for (int l=0; l<3; l++){
        {   // K1: tile bits = global {0,1} + {10..19}; digit j at t-pos 2*(j-4)-... d5->2,d6->4,d7->6,d8->8,d9->10
            FusedCfg c{};
            c.um0=0x3u;  c.us0=0; c.um1=0xFFCu; c.us1=8; c.bs0=2;
            c.nops=4; c.doInit=(l==0);
            int PA[4]={10,8,6,4}, PB[4]={8,6,4,2};
            for (int i=0;i<4;i++){ c.pa[i]=PA[i]; c.pb[i]=PB[i]; c.preA[i]=-1; c.preB[i]=(l*10+i+1)*16; }
            c.preA[0]=(l*10+0)*16;
            fused_ops<<<256, 256, 0, stream>>>(rho, mats, c);
        }
        {   // K2: tile bits = global {0..11} (identity); d1->2,d2->4,d3->6,d4->8,d5->10
            FusedCfg c{};
            c.um0=0xFFFu; c.us0=0; c.um1=0; c.us1=0; c.bs0=12;
            c.nops=4; c.doInit=0;
            int PA[4]={10,8,6,4}, PB[4]={8,6,4,2};
            for (int i=0;i<4;i++){ c.pa[i]=PA[i]; c.pb[i]=PB[i]; c.preA[i]=-1; c.preB[i]=(l*10+i+5)*16; }
            fused_ops<<<256, 256, 0, stream>>>(rho, mats, c);
        }
        {   // K3: tile bits = global {0..9} + {18,19}; d0->0, d1->2, d9->10
            FusedCfg c{};
            c.um0=0x3FFu; c.us0=0; c.um1=0xC00u; c.us1=8; c.bs0=10;
            c.nops=2; c.doInit=0;
            c.pa[0]=2;  c.pb[0]=0;  c.preA[0]=-1; c.preB[0]=(l*10+9)*16;  // CNOT(8,9), preB=Rot(9)
            c.pa[1]=0;  c.pb[1]=10; c.preA[1]=-1; c.preB[1]=-1;           // CNOT(9,0)
            c.pa[2]=0;  c.pb[2]=2;  c.preA[2]=-1; c.preB[2]=-1;           // unused
            c.pa[3]=0;  c.pb[3]=2;  c.preA[3]=-1; c.preB[3]=-1;           // unused
            fused_ops<<<256, 256, 0, stream>>>(rho, mats, c);
        }
    }

    trace_kernel<<<20, 256, 0, stream>>>(rho, w, cvec);
    logits_kernel<<<2048, 256, 0, stream>>>(x, bvec, cvec, out);
}